// Round 1
// baseline (66.905 us; speedup 1.0000x reference)
//
#include <hip/hip_runtime.h>

// Gram matrix lower-tri extraction: out[b, i*(i-1)/2 + j] = sum_d X[b,i,d]*X[b,j,d], i>j
// B=8192, N=64, D=128, fp32 in/out. bf16 MFMA (16x16x32), one wave per sample, no LDS.

typedef __attribute__((ext_vector_type(8))) short bf16x8;
typedef __attribute__((ext_vector_type(4))) float f32x4;

__device__ inline unsigned short f2bf(float f) {
    // round-to-nearest-even fp32 -> bf16 (inputs are finite normals; NaN path not needed)
    unsigned int u = __float_as_uint(f);
    u += 0x7fffu + ((u >> 16) & 1u);
    return (unsigned short)(u >> 16);
}

__global__ __launch_bounds__(256) void gram_tril_kernel(const float* __restrict__ X,
                                                        float* __restrict__ out) {
    const int wave = threadIdx.x >> 6;
    const int lane = threadIdx.x & 63;
    const int b = blockIdx.x * 4 + wave;

    const float* __restrict__ Xb = X + (size_t)b * (64 * 128);
    const int lr = lane & 15;   // row within 16-row block (A) / col within tile (B)
    const int lg = lane >> 4;   // k-group (8 contiguous k each)

    // Load all 16 fragments (4 row-blocks x 4 k-steps), fp32 -> bf16.
    // Each element of X read exactly once across the wave.
    bf16x8 frag[4][4];
#pragma unroll
    for (int ti = 0; ti < 4; ++ti) {
#pragma unroll
        for (int ks = 0; ks < 4; ++ks) {
            const float* p = Xb + (size_t)(ti * 16 + lr) * 128 + ks * 32 + lg * 8;
            const float4 a = *(const float4*)p;
            const float4 c = *(const float4*)(p + 4);
            bf16x8 f;
            f[0] = (short)f2bf(a.x); f[1] = (short)f2bf(a.y);
            f[2] = (short)f2bf(a.z); f[3] = (short)f2bf(a.w);
            f[4] = (short)f2bf(c.x); f[5] = (short)f2bf(c.y);
            f[6] = (short)f2bf(c.z); f[7] = (short)f2bf(c.w);
            frag[ti][ks] = f;
        }
    }

    float* __restrict__ ob = out + (size_t)b * 2016;

    // 10 lower-tri tiles (ti >= tj); diagonal tiles masked to strict-lower.
#pragma unroll
    for (int ti = 0; ti < 4; ++ti) {
#pragma unroll
        for (int tj = 0; tj <= ti; ++tj) {
            f32x4 acc = {0.f, 0.f, 0.f, 0.f};
#pragma unroll
            for (int ks = 0; ks < 4; ++ks) {
                acc = __builtin_amdgcn_mfma_f32_16x16x32_bf16(frag[ti][ks], frag[tj][ks],
                                                              acc, 0, 0, 0);
            }
            const int j = tj * 16 + lr;  // C/D: col = lane&15
#pragma unroll
            for (int r = 0; r < 4; ++r) {
                const int i = ti * 16 + lg * 4 + r;  // C/D: row = (lane>>4)*4 + reg
                if (ti > tj || i > j) {
                    ob[(i * (i - 1)) / 2 + j] = acc[r];
                }
            }
        }
    }
}

extern "C" void kernel_launch(void* const* d_in, const int* in_sizes, int n_in,
                              void* d_out, int out_size, void* d_ws, size_t ws_size,
                              hipStream_t stream) {
    const float* X = (const float*)d_in[0];
    float* out = (float*)d_out;
    const int B = in_sizes[0] / (64 * 128);  // 8192
    const int blocks = B / 4;                // 4 waves/block, 1 sample/wave
    gram_tril_kernel<<<blocks, 256, 0, stream>>>(X, out);
}